// Round 11
// baseline (11658.253 us; speedup 1.0000x reference)
//
#include <hip/hip_runtime.h>
#include <math.h>

#define T_LEN   1024
#define S_SEAS  168
#define H_SZ    128
#define G_SZ    512   // 4*H
#define WIN_SZ  168
#define OUT_SZ  24
#define N_WIN   833
#define BB      16
#define NBLK    ((N_WIN + BB - 1) / BB)   // 53
#define NPAD    (NBLK * BB)               // 848

typedef __attribute__((ext_vector_type(8))) __bf16 bf16x8;
typedef __attribute__((ext_vector_type(4))) float  f32x4;

__device__ __forceinline__ float fsig(float x) {
    return __fdividef(1.0f, 1.0f + __expf(-x));
}
__device__ __forceinline__ float ftanh(float x) {
    return 1.0f - __fdividef(2.0f, __expf(2.0f * x) + 1.0f);
}

// Counted-wait barrier: order LDS only; globals ride across (T3/T4).
#define LDS_BARRIER()                                        \
    do {                                                     \
        asm volatile("s_waitcnt lgkmcnt(0)" ::: "memory");   \
        __builtin_amdgcn_s_barrier();                        \
    } while (0)

// ---------------------------------------------------------------------------
// Kernel 1: es_scan (block 0) + weight prep (blocks 1..160).  [r8 config]
// ---------------------------------------------------------------------------
__global__ __launch_bounds__(256) void pre_kernel(
    const float* __restrict__ x,
    const float* __restrict__ lvl_raw,
    const float* __restrict__ seas_raw,
    const float* __restrict__ seas_params,
    const float* __restrict__ Wh0,
    const float* __restrict__ Wx1,
    const float* __restrict__ Wh1,
    const float* __restrict__ tanhW,
    float* __restrict__ levels,
    float* __restrict__ wsv,
    uint4* __restrict__ pw0,
    uint4* __restrict__ pw1,
    float* __restrict__ tanhWT) {
    __shared__ float xl[T_LEN];
    __shared__ float buf[S_SEAS];
    const int t = threadIdx.x;

    if (blockIdx.x == 0) {
        for (int i = t; i < T_LEN; i += 256) xl[i] = x[i];
        for (int i = t; i < S_SEAS; i += 256) {
            const float w = expf(seas_params[i]);
            buf[i] = w;
            wsv[i] = w;
        }
        __syncthreads();
        if (t == 0) {
            const float a  = 1.0f / (1.0f + expf(-lvl_raw[0]));
            const float g  = 1.0f / (1.0f + expf(-seas_raw[0]));
            const float ca = 1.0f - a, cg = 1.0f - g;
            float level = __fdividef(xl[0], buf[0]);
            levels[0] = level;
            wsv[S_SEAS] = buf[0];   // ws_full[168] = w_init[0]

            float wq[8], tq[8];
#pragma unroll
            for (int k = 0; k < 8; ++k) {
                const int i = 1 + k;
                const float w = buf[i % S_SEAS];
                wq[k] = w;
                tq[k] = __fdividef(a * xl[i], w);
            }
            for (int i = 1; i < T_LEN; i += 8) {
#pragma unroll
                for (int s = 0; s < 8; ++s) {
                    const int ii = i + s;
                    if (ii >= T_LEN) break;
                    const float w  = wq[s];
                    const float nl = tq[s] + ca * level;   // chain: 1 FMA
                    const float nw = cg * w + __fdividef(g * xl[ii], nl);
                    levels[ii] = nl;
                    buf[ii % S_SEAS] = nw;
                    if (ii + S_SEAS < T_LEN) wsv[ii + S_SEAS] = nw;
                    level = nl;
                    const int i8 = ii + 8;
                    if (i8 < T_LEN) {
                        const float w8 = buf[i8 % S_SEAS];
                        wq[s] = w8;
                        tq[s] = __fdividef(a * xl[i8], w8);
                    }
                }
            }
        }
        return;
    }

    const int idx = (blockIdx.x - 1) * 256 + t;
    auto bfr = [](float f) -> unsigned int {   // fp32 -> bf16 (RNE)
        union { float f; unsigned int u; } v; v.f = f;
        return ((v.u + 0x7FFFu + ((v.u >> 16) & 1u)) >> 16) & 0xFFFFu;
    };
    if (idx < 8192) {                       // pw0: Wh0, 128 frags
        const int l = idx & 63, f = idx >> 6;
        const int kt = f & 3, ns = (f >> 2) & 3, w = f >> 4;
        const int g = ns * 128 + w * 16 + (l & 15);
        const int kb = kt * 32 + (l >> 4) * 8;
        const float* s = Wh0 + g * H_SZ + kb;
        uint4 o;
        unsigned int* po = &o.x;
        for (int p = 0; p < 4; ++p) po[p] = bfr(s[2 * p]) | (bfr(s[2 * p + 1]) << 16);
        pw0[idx] = o;
    } else if (idx < 8192 + 16384) {        // pw1: [Wx1 (kt<4); Wh1 (kt>=4)]
        const int j = idx - 8192;
        const int l = j & 63, f = j >> 6;
        const int kt = f & 7, ns = (f >> 3) & 3, w = f >> 5;
        const int g = ns * 128 + w * 16 + (l & 15);
        const float* srcm = (kt < 4) ? Wx1 : Wh1;
        const int kb = (kt & 3) * 32 + (l >> 4) * 8;
        const float* s = srcm + g * H_SZ + kb;
        uint4 o;
        unsigned int* po = &o.x;
        for (int p = 0; p < 4; ++p) po[p] = bfr(s[2 * p]) | (bfr(s[2 * p + 1]) << 16);
        pw1[j] = o;
    } else if (idx < 8192 + 16384 + 16384) {  // tanh_W transpose (fp32)
        const int j = idx - 8192 - 16384;
        const int m = j >> 7, k = j & 127;
        tanhWT[k * H_SZ + m] = tanhW[j];
    }
}

// ---------------------------------------------------------------------------
// Kernel 2: layer-0 LSTM  [r8 config]
// ---------------------------------------------------------------------------
__global__ __launch_bounds__(512, 2) void l0_kernel(
    const float* __restrict__ x,
    const float* __restrict__ levels,
    const float* __restrict__ wsv,
    const float* __restrict__ noise_in,
    const float* __restrict__ Wx0,
    const float* __restrict__ b0v,
    const uint4* __restrict__ pw0,
    __bf16* __restrict__ hs0) {
    __shared__ __bf16 h0s[2][16 * 128];
    __shared__ float  xls[WIN_SZ][16];

    const int tid  = threadIdx.x;
    const int w    = tid >> 6;
    const int lane = tid & 63;
    const int cc   = lane & 15;
    const int kl   = lane >> 4;
    const int base = blockIdx.x * BB;

    for (int i = tid; i < WIN_SZ * BB; i += 512) {
        const int t = i >> 4, m = i & 15;
        const int nn = base + m;
        float v = 0.0f;
        if (nn < N_WIN) {
            const float lev = levels[nn + WIN_SZ];
            const int tt = nn + t;
            v = logf(x[tt] / (lev * wsv[tt])) + noise_in[nn * WIN_SZ + t];
        }
        xls[t][m] = v;
    }
    for (int i = tid; i < 2 * 16 * 128; i += 512) (&h0s[0][0])[i] = (__bf16)0.0f;

    const bf16x8* p0 = (const bf16x8*)pw0;
    bf16x8 wB0[4][4];
#pragma unroll
    for (int ns = 0; ns < 4; ++ns)
#pragma unroll
        for (int kt = 0; kt < 4; ++kt)
            wB0[ns][kt] = p0[((w * 4 + ns) * 4 + kt) * 64 + lane];
#pragma unroll
    for (int ns = 0; ns < 4; ++ns)
#pragma unroll
        for (int kt = 0; kt < 4; ++kt)
            asm("" : "+a"(wB0[ns][kt]));

    float b0r[4], wx0r[4];
#pragma unroll
    for (int ns = 0; ns < 4; ++ns) {
        const int g = ns * 128 + w * 16 + cc;
        b0r[ns]  = b0v[g];
        wx0r[ns] = Wx0[g];
    }
    float c0r[4] = {0.f, 0.f, 0.f, 0.f};

    int rdA[4], wrA[4], goff[4];
#pragma unroll
    for (int kt = 0; kt < 4; ++kt)
        rdA[kt] = cc * 256 + ((kt * 64 + kl * 16) ^ ((cc & 7) << 4));
#pragma unroll
    for (int r = 0; r < 4; ++r) {
        const int row = kl * 4 + r;
        wrA[r]  = row * 256 + (((w * 16 + cc) * 2) ^ ((row & 7) << 4));
        goff[r] = (base + row) * H_SZ + w * 16 + cc;
    }
    __syncthreads();

    char* const hb0 = (char*)&h0s[0][0];

#define L0_STEP(T, P)                                                          \
    {                                                                          \
        const int t_ = (T);                                                    \
        const float4 xt_ = *(const float4*)&xls[t_][kl * 4];                   \
        const float xa_[4] = {xt_.x, xt_.y, xt_.z, xt_.w};                     \
        f32x4 a0_, a1_, a2_, a3_;                                              \
        _Pragma("unroll")                                                      \
        for (int r = 0; r < 4; ++r) {                                          \
            a0_[r] = b0r[0] + wx0r[0] * xa_[r];                                \
            a1_[r] = b0r[1] + wx0r[1] * xa_[r];                                \
            a2_[r] = b0r[2] + wx0r[2] * xa_[r];                                \
            a3_[r] = b0r[3] + wx0r[3] * xa_[r];                                \
        }                                                                      \
        _Pragma("unroll")                                                      \
        for (int kt = 0; kt < 4; ++kt) {                                       \
            const bf16x8 af_ = *(const bf16x8*)(hb0 + (P) * 4096 + rdA[kt]);   \
            a0_ = __builtin_amdgcn_mfma_f32_16x16x32_bf16(af_, wB0[0][kt], a0_, 0, 0, 0); \
            a1_ = __builtin_amdgcn_mfma_f32_16x16x32_bf16(af_, wB0[1][kt], a1_, 0, 0, 0); \
            a2_ = __builtin_amdgcn_mfma_f32_16x16x32_bf16(af_, wB0[2][kt], a2_, 0, 0, 0); \
            a3_ = __builtin_amdgcn_mfma_f32_16x16x32_bf16(af_, wB0[3][kt], a3_, 0, 0, 0); \
        }                                                                      \
        const int off_ = t_ * (NPAD * H_SZ);                                   \
        _Pragma("unroll")                                                      \
        for (int r = 0; r < 4; ++r) {                                          \
            const float ig_ = fsig(a0_[r]);                                    \
            const float fg_ = fsig(a1_[r]);                                    \
            const float gg_ = ftanh(a2_[r]);                                   \
            const float og_ = fsig(a3_[r]);                                    \
            const float c_  = fg_ * c0r[r] + ig_ * gg_;                        \
            c0r[r] = c_;                                                       \
            const __bf16 hb_ = (__bf16)(og_ * ftanh(c_));                      \
            *(__bf16*)(hb0 + (((P) ^ 1) * 4096) + wrA[r]) = hb_;               \
            hs0[off_ + goff[r]] = hb_;                                         \
        }                                                                      \
        LDS_BARRIER();                                                         \
    }

    for (int tp = 0; tp < WIN_SZ / 2; ++tp) {
        L0_STEP(2 * tp, 0)
        L0_STEP(2 * tp + 1, 1)
    }
#undef L0_STEP
}

// ---------------------------------------------------------------------------
// Kernel 3: layer-1 LSTM + head + labels  [r8 config]
// ---------------------------------------------------------------------------
__global__ __launch_bounds__(512, 2) void l1_kernel(
    const __bf16* __restrict__ hs0,
    const float* __restrict__ b1v,
    const uint4* __restrict__ pw1,
    const float* __restrict__ tanhWT,
    const float* __restrict__ tanhB,
    const float* __restrict__ linW,
    const float* __restrict__ linB,
    const float* __restrict__ x,
    const float* __restrict__ levels,
    const float* __restrict__ wsv,
    const float* __restrict__ noise_lab,
    float* __restrict__ out) {
    __shared__ __bf16 h1s[2][16 * 128];
    __shared__ float  hfl[16][129];
    __shared__ float  featl[16][128];

    const int tid  = threadIdx.x;
    const int w    = tid >> 6;
    const int lane = tid & 63;
    const int cc   = lane & 15;
    const int kl   = lane >> 4;
    const int base = blockIdx.x * BB;

    for (int i = tid; i < 2 * 16 * 128; i += 512) (&h1s[0][0])[i] = (__bf16)0.0f;

    const bf16x8* p1 = (const bf16x8*)pw1;
    bf16x8 wX[4][4], wH[4][4];
#pragma unroll
    for (int ns = 0; ns < 4; ++ns)
#pragma unroll
        for (int kt = 0; kt < 4; ++kt) {
            wX[ns][kt] = p1[((w * 4 + ns) * 8 + kt) * 64 + lane];
            wH[ns][kt] = p1[((w * 4 + ns) * 8 + kt + 4) * 64 + lane];
        }
#pragma unroll
    for (int ns = 0; ns < 4; ++ns)
#pragma unroll
        for (int kt = 0; kt < 4; ++kt) {
            asm("" : "+a"(wX[ns][kt]));
            asm("" : "+a"(wH[ns][kt]));
        }

    float b1r[4];
#pragma unroll
    for (int ns = 0; ns < 4; ++ns) b1r[ns] = b1v[ns * 128 + w * 16 + cc];
    float c1r[4] = {0.f, 0.f, 0.f, 0.f};

    int rdA[4], wrA[4];
#pragma unroll
    for (int kt = 0; kt < 4; ++kt)
        rdA[kt] = cc * 256 + ((kt * 64 + kl * 16) ^ ((cc & 7) << 4));
#pragma unroll
    for (int r = 0; r < 4; ++r) {
        const int row = kl * 4 + r;
        wrA[r] = row * 256 + (((w * 16 + cc) * 2) ^ ((row & 7) << 4));
    }

    const size_t arow = (size_t)(base + cc) * H_SZ + kl * 8;
    bf16x8 fA0 = *(const bf16x8*)&hs0[arow + 0];
    bf16x8 fA1 = *(const bf16x8*)&hs0[arow + 32];
    bf16x8 fA2 = *(const bf16x8*)&hs0[arow + 64];
    bf16x8 fA3 = *(const bf16x8*)&hs0[arow + 96];
    bf16x8 fB0, fB1, fB2, fB3;
    __syncthreads();

    char* const hb1 = (char*)&h1s[0][0];

#define L1_STEP(T, P, C0, C1, C2, C3, N0, N1, N2, N3)                          \
    {                                                                          \
        const int t_ = (T);                                                    \
        const int tn_ = (t_ + 1 < WIN_SZ) ? (t_ + 1) : (WIN_SZ - 1);           \
        const __bf16* p_ = hs0 + (size_t)tn_ * (NPAD * H_SZ) + arow;           \
        N0 = *(const bf16x8*)(p_);                                             \
        N1 = *(const bf16x8*)(p_ + 32);                                        \
        N2 = *(const bf16x8*)(p_ + 64);                                        \
        N3 = *(const bf16x8*)(p_ + 96);                                        \
        f32x4 a0_ = {b1r[0], b1r[0], b1r[0], b1r[0]};                          \
        f32x4 a1_ = {b1r[1], b1r[1], b1r[1], b1r[1]};                          \
        f32x4 a2_ = {b1r[2], b1r[2], b1r[2], b1r[2]};                          \
        f32x4 a3_ = {b1r[3], b1r[3], b1r[3], b1r[3]};                          \
        a0_ = __builtin_amdgcn_mfma_f32_16x16x32_bf16(C0, wX[0][0], a0_, 0, 0, 0); \
        a1_ = __builtin_amdgcn_mfma_f32_16x16x32_bf16(C0, wX[1][0], a1_, 0, 0, 0); \
        a2_ = __builtin_amdgcn_mfma_f32_16x16x32_bf16(C0, wX[2][0], a2_, 0, 0, 0); \
        a3_ = __builtin_amdgcn_mfma_f32_16x16x32_bf16(C0, wX[3][0], a3_, 0, 0, 0); \
        a0_ = __builtin_amdgcn_mfma_f32_16x16x32_bf16(C1, wX[0][1], a0_, 0, 0, 0); \
        a1_ = __builtin_amdgcn_mfma_f32_16x16x32_bf16(C1, wX[1][1], a1_, 0, 0, 0); \
        a2_ = __builtin_amdgcn_mfma_f32_16x16x32_bf16(C1, wX[2][1], a2_, 0, 0, 0); \
        a3_ = __builtin_amdgcn_mfma_f32_16x16x32_bf16(C1, wX[3][1], a3_, 0, 0, 0); \
        a0_ = __builtin_amdgcn_mfma_f32_16x16x32_bf16(C2, wX[0][2], a0_, 0, 0, 0); \
        a1_ = __builtin_amdgcn_mfma_f32_16x16x32_bf16(C2, wX[1][2], a1_, 0, 0, 0); \
        a2_ = __builtin_amdgcn_mfma_f32_16x16x32_bf16(C2, wX[2][2], a2_, 0, 0, 0); \
        a3_ = __builtin_amdgcn_mfma_f32_16x16x32_bf16(C2, wX[3][2], a3_, 0, 0, 0); \
        a0_ = __builtin_amdgcn_mfma_f32_16x16x32_bf16(C3, wX[0][3], a0_, 0, 0, 0); \
        a1_ = __builtin_amdgcn_mfma_f32_16x16x32_bf16(C3, wX[1][3], a1_, 0, 0, 0); \
        a2_ = __builtin_amdgcn_mfma_f32_16x16x32_bf16(C3, wX[2][3], a2_, 0, 0, 0); \
        a3_ = __builtin_amdgcn_mfma_f32_16x16x32_bf16(C3, wX[3][3], a3_, 0, 0, 0); \
        _Pragma("unroll")                                                      \
        for (int kt = 0; kt < 4; ++kt) {                                       \
            const bf16x8 af_ = *(const bf16x8*)(hb1 + (P) * 4096 + rdA[kt]);   \
            a0_ = __builtin_amdgcn_mfma_f32_16x16x32_bf16(af_, wH[0][kt], a0_, 0, 0, 0); \
            a1_ = __builtin_amdgcn_mfma_f32_16x16x32_bf16(af_, wH[1][kt], a1_, 0, 0, 0); \
            a2_ = __builtin_amdgcn_mfma_f32_16x16x32_bf16(af_, wH[2][kt], a2_, 0, 0, 0); \
            a3_ = __builtin_amdgcn_mfma_f32_16x16x32_bf16(af_, wH[3][kt], a3_, 0, 0, 0); \
        }                                                                      \
        _Pragma("unroll")                                                      \
        for (int r = 0; r < 4; ++r) {                                          \
            const float ig_ = fsig(a0_[r]);                                    \
            const float fg_ = fsig(a1_[r]);                                    \
            const float gg_ = ftanh(a2_[r]);                                   \
            const float og_ = fsig(a3_[r]);                                    \
            const float c_  = fg_ * c1r[r] + ig_ * gg_;                        \
            c1r[r] = c_;                                                       \
            const float hv_ = og_ * ftanh(c_);                                 \
            if (t_ == WIN_SZ - 1) {                                            \
                hfl[kl * 4 + r][w * 16 + cc] = hv_;                            \
            } else {                                                           \
                *(__bf16*)(hb1 + (((P) ^ 1) * 4096) + wrA[r]) = (__bf16)hv_;   \
            }                                                                  \
        }                                                                      \
        LDS_BARRIER();                                                         \
    }

    for (int tp = 0; tp < WIN_SZ / 2; ++tp) {
        L1_STEP(2 * tp, 0, fA0, fA1, fA2, fA3, fB0, fB1, fB2, fB3)
        L1_STEP(2 * tp + 1, 1, fB0, fB1, fB2, fB3, fA0, fA1, fA2, fA3)
    }
#undef L1_STEP

    for (int p = tid; p < BB * H_SZ; p += 512) {
        const int m = p >> 7, u = p & 127;
        float acc = tanhB[u];
        for (int k = 0; k < H_SZ; ++k)
            acc += hfl[m][k] * tanhWT[k * H_SZ + u];
        featl[m][u] = tanhf(acc);
    }
    LDS_BARRIER();

    for (int p = tid; p < BB * OUT_SZ; p += 512) {
        const int m = p / OUT_SZ, o = p % OUT_SZ;
        const int nn = base + m;
        if (nn < N_WIN) {
            float acc = linB[o];
            for (int k = 0; k < H_SZ; ++k)
                acc += featl[m][k] * linW[o * H_SZ + k];
            out[nn * OUT_SZ + o] = acc;
            const float lev = levels[nn + WIN_SZ];
            const int tt = nn + WIN_SZ + o;
            out[N_WIN * OUT_SZ + nn * OUT_SZ + o] =
                logf(x[tt] / (lev * wsv[tt])) + noise_lab[nn * OUT_SZ + o];
        }
    }
    if (blockIdx.x == 0 && tid == 0)
        out[2 * N_WIN * OUT_SZ] = 0.0f;   // level_var_loss
}

// ---------------------------------------------------------------------------
// DIAGNOSTIC PROBES (outputs go to ws scratch; results never touch d_out).
// V=0 full | 1 noTrans | 2 noMFMA | 3 noBarrier | 4 skeleton(noMFMA+noTrans)
// 8*168 steps so each probe ranks in rocprof top-5.
// ---------------------------------------------------------------------------
template<int V>
__global__ __launch_bounds__(512, 2) void probe_kernel(
    const __bf16* __restrict__ hs0,
    const float* __restrict__ b1v,
    const uint4* __restrict__ pw1,
    float* __restrict__ scratch) {
    constexpr bool DO_MFMA  = (V != 2 && V != 4);
    constexpr bool DO_TRANS = (V != 1 && V != 4);
    constexpr bool DO_BAR   = (V != 3);

    __shared__ __bf16 h1s[2][16 * 128];
    const int tid  = threadIdx.x;
    const int w    = tid >> 6;
    const int lane = tid & 63;
    const int cc   = lane & 15;
    const int kl   = lane >> 4;
    const int base = blockIdx.x * BB;

    for (int i = tid; i < 2 * 16 * 128; i += 512) (&h1s[0][0])[i] = (__bf16)0.0f;

    const bf16x8* p1 = (const bf16x8*)pw1;
    bf16x8 wX[4][4], wH[4][4];
#pragma unroll
    for (int ns = 0; ns < 4; ++ns)
#pragma unroll
        for (int kt = 0; kt < 4; ++kt) {
            wX[ns][kt] = p1[((w * 4 + ns) * 8 + kt) * 64 + lane];
            wH[ns][kt] = p1[((w * 4 + ns) * 8 + kt + 4) * 64 + lane];
        }
#pragma unroll
    for (int ns = 0; ns < 4; ++ns)
#pragma unroll
        for (int kt = 0; kt < 4; ++kt) {
            asm("" : "+a"(wX[ns][kt]));
            asm("" : "+a"(wH[ns][kt]));
        }
    if constexpr (!DO_MFMA) {   // keep weight loads live when MFMAs removed
#pragma unroll
        for (int ns = 0; ns < 4; ++ns)
#pragma unroll
            for (int kt = 0; kt < 4; ++kt)
                asm volatile("" :: "a"(wX[ns][kt]), "a"(wH[ns][kt]));
    }

    float b1r[4];
#pragma unroll
    for (int ns = 0; ns < 4; ++ns) b1r[ns] = b1v[ns * 128 + w * 16 + cc];
    float c1r[4] = {0.f, 0.f, 0.f, 0.f};

    int rdA[4], wrA[4];
#pragma unroll
    for (int kt = 0; kt < 4; ++kt)
        rdA[kt] = cc * 256 + ((kt * 64 + kl * 16) ^ ((cc & 7) << 4));
#pragma unroll
    for (int r = 0; r < 4; ++r) {
        const int row = kl * 4 + r;
        wrA[r] = row * 256 + (((w * 16 + cc) * 2) ^ ((row & 7) << 4));
    }

    const size_t arow = (size_t)(base + cc) * H_SZ + kl * 8;
    bf16x8 f0 = *(const bf16x8*)&hs0[arow + 0];
    bf16x8 f1 = *(const bf16x8*)&hs0[arow + 32];
    bf16x8 f2 = *(const bf16x8*)&hs0[arow + 64];
    bf16x8 f3 = *(const bf16x8*)&hs0[arow + 96];
    __syncthreads();

    char* const hb1 = (char*)&h1s[0][0];
    int tnx = 1;

    for (int it = 0; it < 8 * WIN_SZ; ++it) {
        const int P = it & 1;
        const __bf16* p_ = hs0 + (size_t)tnx * (NPAD * H_SZ) + arow;
        bf16x8 g0 = *(const bf16x8*)(p_);
        bf16x8 g1 = *(const bf16x8*)(p_ + 32);
        bf16x8 g2 = *(const bf16x8*)(p_ + 64);
        bf16x8 g3 = *(const bf16x8*)(p_ + 96);
        tnx = (tnx + 1 == WIN_SZ) ? 0 : tnx + 1;

        f32x4 a0_ = {b1r[0], b1r[0], b1r[0], b1r[0]};
        f32x4 a1_ = {b1r[1], b1r[1], b1r[1], b1r[1]};
        f32x4 a2_ = {b1r[2], b1r[2], b1r[2], b1r[2]};
        f32x4 a3_ = {b1r[3], b1r[3], b1r[3], b1r[3]};

        if constexpr (DO_MFMA) {
            a0_ = __builtin_amdgcn_mfma_f32_16x16x32_bf16(f0, wX[0][0], a0_, 0, 0, 0);
            a1_ = __builtin_amdgcn_mfma_f32_16x16x32_bf16(f0, wX[1][0], a1_, 0, 0, 0);
            a2_ = __builtin_amdgcn_mfma_f32_16x16x32_bf16(f0, wX[2][0], a2_, 0, 0, 0);
            a3_ = __builtin_amdgcn_mfma_f32_16x16x32_bf16(f0, wX[3][0], a3_, 0, 0, 0);
            a0_ = __builtin_amdgcn_mfma_f32_16x16x32_bf16(f1, wX[0][1], a0_, 0, 0, 0);
            a1_ = __builtin_amdgcn_mfma_f32_16x16x32_bf16(f1, wX[1][1], a1_, 0, 0, 0);
            a2_ = __builtin_amdgcn_mfma_f32_16x16x32_bf16(f1, wX[2][1], a2_, 0, 0, 0);
            a3_ = __builtin_amdgcn_mfma_f32_16x16x32_bf16(f1, wX[3][1], a3_, 0, 0, 0);
            a0_ = __builtin_amdgcn_mfma_f32_16x16x32_bf16(f2, wX[0][2], a0_, 0, 0, 0);
            a1_ = __builtin_amdgcn_mfma_f32_16x16x32_bf16(f2, wX[1][2], a1_, 0, 0, 0);
            a2_ = __builtin_amdgcn_mfma_f32_16x16x32_bf16(f2, wX[2][2], a2_, 0, 0, 0);
            a3_ = __builtin_amdgcn_mfma_f32_16x16x32_bf16(f2, wX[3][2], a3_, 0, 0, 0);
            a0_ = __builtin_amdgcn_mfma_f32_16x16x32_bf16(f3, wX[0][3], a0_, 0, 0, 0);
            a1_ = __builtin_amdgcn_mfma_f32_16x16x32_bf16(f3, wX[1][3], a1_, 0, 0, 0);
            a2_ = __builtin_amdgcn_mfma_f32_16x16x32_bf16(f3, wX[2][3], a2_, 0, 0, 0);
            a3_ = __builtin_amdgcn_mfma_f32_16x16x32_bf16(f3, wX[3][3], a3_, 0, 0, 0);
#pragma unroll
            for (int kt = 0; kt < 4; ++kt) {
                const bf16x8 af_ = *(const bf16x8*)(hb1 + P * 4096 + rdA[kt]);
                a0_ = __builtin_amdgcn_mfma_f32_16x16x32_bf16(af_, wH[0][kt], a0_, 0, 0, 0);
                a1_ = __builtin_amdgcn_mfma_f32_16x16x32_bf16(af_, wH[1][kt], a1_, 0, 0, 0);
                a2_ = __builtin_amdgcn_mfma_f32_16x16x32_bf16(af_, wH[2][kt], a2_, 0, 0, 0);
                a3_ = __builtin_amdgcn_mfma_f32_16x16x32_bf16(af_, wH[3][kt], a3_, 0, 0, 0);
            }
        } else {
            // keep global-prefetch + ds_read dependencies without MFMA
            a0_ += __builtin_bit_cast(f32x4, f0);
            a1_ += __builtin_bit_cast(f32x4, f1);
            a2_ += __builtin_bit_cast(f32x4, f2);
            a3_ += __builtin_bit_cast(f32x4, f3);
#pragma unroll
            for (int kt = 0; kt < 4; ++kt) {
                const bf16x8 af_ = *(const bf16x8*)(hb1 + P * 4096 + rdA[kt]);
                const f32x4 fv_ = __builtin_bit_cast(f32x4, af_);
                if (kt == 0) a0_ += fv_;
                if (kt == 1) a1_ += fv_;
                if (kt == 2) a2_ += fv_;
                if (kt == 3) a3_ += fv_;
            }
        }

#pragma unroll
        for (int r = 0; r < 4; ++r) {
            float ig_, fg_, gg_, og_, th_;
            if constexpr (DO_TRANS) {
                ig_ = fsig(a0_[r]);
                fg_ = fsig(a1_[r]);
                gg_ = ftanh(a2_[r]);
                og_ = fsig(a3_[r]);
            } else {
                ig_ = 0.5f + 0.25f * a0_[r];
                fg_ = 0.5f + 0.25f * a1_[r];
                gg_ = 0.98f * a2_[r];
                og_ = 0.5f + 0.25f * a3_[r];
            }
            const float c_ = fg_ * c1r[r] + ig_ * gg_;
            c1r[r] = c_;
            if constexpr (DO_TRANS) th_ = ftanh(c_);
            else                    th_ = 0.98f * c_;
            *(__bf16*)(hb1 + ((P ^ 1) * 4096) + wrA[r]) = (__bf16)(og_ * th_);
        }
        if constexpr (DO_BAR) LDS_BARRIER();
        f0 = g0; f1 = g1; f2 = g2; f3 = g3;
    }

    // keep everything live; scratch is write-only diagnostics
    float s = c1r[0] + c1r[1] + c1r[2] + c1r[3]
            + (float)*(__bf16*)(hb1 + (tid * 2 & 4095));
    scratch[blockIdx.x * 512 + tid] = s;
}

// ---------------------------------------------------------------------------
extern "C" void kernel_launch(void* const* d_in, const int* in_sizes, int n_in,
                              void* d_out, int out_size, void* d_ws, size_t ws_size,
                              hipStream_t stream) {
    const float* x           = (const float*)d_in[0];
    const float* lvl_raw     = (const float*)d_in[1];
    const float* seas_raw    = (const float*)d_in[2];
    const float* seas_params = (const float*)d_in[3];
    const float* noise_in    = (const float*)d_in[4];
    const float* noise_lab   = (const float*)d_in[5];
    const float* Wx0         = (const float*)d_in[6];
    const float* Wh0         = (const float*)d_in[7];
    const float* b0v         = (const float*)d_in[8];
    const float* Wx1         = (const float*)d_in[9];
    const float* Wh1         = (const float*)d_in[10];
    const float* b1v         = (const float*)d_in[11];
    const float* tanhW       = (const float*)d_in[12];
    const float* tanhB       = (const float*)d_in[13];
    const float* linW        = (const float*)d_in[14];
    const float* linB        = (const float*)d_in[15];
    float* out = (float*)d_out;

    float* wsf    = (float*)d_ws;
    float* levels = wsf;                                   // 1024
    float* wsv    = levels + T_LEN;                        // 1024
    float* tanhWT = wsv + T_LEN;                           // 16384
    uint4* pw0    = (uint4*)(tanhWT + H_SZ * H_SZ);        // 8192 uint4
    uint4* pw1    = pw0 + 8192;                            // 16384 uint4
    __bf16* hs0   = (__bf16*)(pw1 + 16384);                // 168*848*128 bf16
    float* scratch = (float*)(hs0 + (size_t)WIN_SZ * NPAD * H_SZ);  // 53*512

    hipLaunchKernelGGL(pre_kernel, dim3(161), dim3(256), 0, stream,
                       x, lvl_raw, seas_raw, seas_params, Wh0, Wx1, Wh1, tanhW,
                       levels, wsv, pw0, pw1, tanhWT);
    hipLaunchKernelGGL(l0_kernel, dim3(NBLK), dim3(512), 0, stream,
                       x, levels, wsv, noise_in, Wx0, b0v, pw0, hs0);
    hipLaunchKernelGGL(l1_kernel, dim3(NBLK), dim3(512), 0, stream,
                       hs0, b1v, pw1, tanhWT, tanhB, linW, linB,
                       x, levels, wsv, noise_lab, out);

    // ---- diagnostic probes (write to scratch only) ----
    hipLaunchKernelGGL((probe_kernel<0>), dim3(NBLK), dim3(512), 0, stream,
                       hs0, b1v, pw1, scratch);
    hipLaunchKernelGGL((probe_kernel<1>), dim3(NBLK), dim3(512), 0, stream,
                       hs0, b1v, pw1, scratch);
    hipLaunchKernelGGL((probe_kernel<2>), dim3(NBLK), dim3(512), 0, stream,
                       hs0, b1v, pw1, scratch);
    hipLaunchKernelGGL((probe_kernel<3>), dim3(NBLK), dim3(512), 0, stream,
                       hs0, b1v, pw1, scratch);
    hipLaunchKernelGGL((probe_kernel<4>), dim3(NBLK), dim3(512), 0, stream,
                       hs0, b1v, pw1, scratch);
}

// Round 12
// 357.739 us; speedup vs baseline: 32.5888x; 32.5888x over previous
//
#include <hip/hip_runtime.h>
#include <math.h>

#define T_LEN   1024
#define S_SEAS  168
#define H_SZ    128
#define G_SZ    512   // 4*H
#define WIN_SZ  168
#define OUT_SZ  24
#define N_WIN   833
#define BB      16
#define NBLK    ((N_WIN + BB - 1) / BB)   // 53
#define NPAD    (NBLK * BB)               // 848

typedef __attribute__((ext_vector_type(8))) __bf16 bf16x8;
typedef __attribute__((ext_vector_type(4))) float  f32x4;

__device__ __forceinline__ float fsig(float x) {
    return __fdividef(1.0f, 1.0f + __expf(-x));
}
__device__ __forceinline__ float ftanh(float x) {
    return 1.0f - __fdividef(2.0f, __expf(2.0f * x) + 1.0f);
}

// Counted-wait barrier: order LDS only; globals ride across (T3/T4).
#define LDS_BARRIER()                                        \
    do {                                                     \
        asm volatile("s_waitcnt lgkmcnt(0)" ::: "memory");   \
        __builtin_amdgcn_s_barrier();                        \
    } while (0)

// ---------------------------------------------------------------------------
// Kernel 1: parallel ES scan (block 0, r10-validated) + weight prep.
// ---------------------------------------------------------------------------
__global__ __launch_bounds__(256) void pre_kernel(
    const float* __restrict__ x,
    const float* __restrict__ lvl_raw,
    const float* __restrict__ seas_raw,
    const float* __restrict__ seas_params,
    const float* __restrict__ Wh0,
    const float* __restrict__ Wx1,
    const float* __restrict__ Wh1,
    const float* __restrict__ tanhW,
    float* __restrict__ levels,
    float* __restrict__ wsv,
    uint4* __restrict__ pw0,
    uint4* __restrict__ pw1,
    float* __restrict__ tanhWT) {
    const int t = threadIdx.x;

    if (blockIdx.x == 0) {
        __shared__ float xl[T_LEN];
        __shared__ float buf[S_SEAS];
        __shared__ float Ss[S_SEAS], Fs[S_SEAS];
        __shared__ float levCarry;
        for (int i = t; i < T_LEN; i += 256) xl[i] = x[i];
        for (int i = t; i < S_SEAS; i += 256) {
            const float w = expf(seas_params[i]);
            buf[i] = w;
            wsv[i] = w;
        }
        __syncthreads();
        const float a  = 1.0f / (1.0f + expf(-lvl_raw[0]));
        const float g  = 1.0f / (1.0f + expf(-seas_raw[0]));
        const float ca = 1.0f - a, cg = 1.0f - g;
        if (t == 0) {
            levCarry = __fdividef(xl[0], buf[0]);
            levels[0] = levCarry;
            wsv[S_SEAS] = buf[0];   // ws_full[168] = w_init[0]
        }
        __syncthreads();

        int cs = 1;
        while (cs < T_LEN) {
            const int L = min(S_SEAS, T_LEN - cs);
            float w = 0.0f;
            if (t < L) {
                const int i = cs + t;
                w = buf[i % S_SEAS];                 // final since step i-168
                Ss[t] = __fdividef(a * xl[i], w);    // t_i
                Fs[t] = ca;
            }
            __syncthreads();
            for (int d = 1; d < L; d <<= 1) {
                float sp = 0.0f, fp = 0.0f;
                const bool act = (t < L) && (t >= d);
                if (act) { sp = Ss[t - d]; fp = Fs[t - d]; }
                __syncthreads();
                if (act) {
                    Ss[t] = Ss[t] + Fs[t] * sp;
                    Fs[t] = Fs[t] * fp;
                }
                __syncthreads();
            }
            if (t < L) {
                const int i = cs + t;
                const float nl = Ss[t] + Fs[t] * levCarry;
                levels[i] = nl;
                const float nw = cg * w + __fdividef(g * xl[i], nl);
                buf[i % S_SEAS] = nw;
                if (i + S_SEAS < T_LEN) wsv[i + S_SEAS] = nw;
            }
            __syncthreads();
            if (t == 0) levCarry = Ss[L - 1] + Fs[L - 1] * levCarry;
            __syncthreads();
            cs += L;
        }
        return;
    }

    // ------- weight prep: pack MFMA B-frags (m92/m97 layout) -------
    const int idx = (blockIdx.x - 1) * 256 + t;
    auto bfr = [](float f) -> unsigned int {   // fp32 -> bf16 (RNE)
        union { float f; unsigned int u; } v; v.f = f;
        return ((v.u + 0x7FFFu + ((v.u >> 16) & 1u)) >> 16) & 0xFFFFu;
    };
    if (idx < 8192) {                       // pw0: Wh0, 128 frags
        const int l = idx & 63, f = idx >> 6;
        const int kt = f & 3, ns = (f >> 2) & 3, w = f >> 4;
        const int g = ns * 128 + w * 16 + (l & 15);
        const int kb = kt * 32 + (l >> 4) * 8;
        const float* s = Wh0 + g * H_SZ + kb;
        uint4 o;
        unsigned int* po = &o.x;
        for (int p = 0; p < 4; ++p) po[p] = bfr(s[2 * p]) | (bfr(s[2 * p + 1]) << 16);
        pw0[idx] = o;
    } else if (idx < 8192 + 16384) {        // pw1: [Wx1 (kt<4); Wh1 (kt>=4)]
        const int j = idx - 8192;
        const int l = j & 63, f = j >> 6;
        const int kt = f & 7, ns = (f >> 3) & 3, w = f >> 5;
        const int g = ns * 128 + w * 16 + (l & 15);
        const float* srcm = (kt < 4) ? Wx1 : Wh1;
        const int kb = (kt & 3) * 32 + (l >> 4) * 8;
        const float* s = srcm + g * H_SZ + kb;
        uint4 o;
        unsigned int* po = &o.x;
        for (int p = 0; p < 4; ++p) po[p] = bfr(s[2 * p]) | (bfr(s[2 * p + 1]) << 16);
        pw1[j] = o;
    } else if (idx < 8192 + 16384 + 16384) {  // tanh_W transpose (fp32)
        const int j = idx - 8192 - 16384;
        const int m = j >> 7, k = j & 127;
        tanhWT[k * H_SZ + m] = tanhW[j];
    }
}

// ---------------------------------------------------------------------------
// Kernel 2: producer/consumer 2-layer LSTM pipeline in ONE launch.
// Blocks 0..52  = layer-0 (r8 l0 body) -> hs0, publish flag[b] every 8 steps
//                 (per-wave vmcnt drain + barrier + agent-release fence).
// Blocks 53..105 = layer-1 (r8 l1 body) + head + labels; acquires flag[b]
//                 before consuming hs0 steps. Register pressure (>=188
//                 regs/wave) forces 1 block/CU -> all 106 blocks co-resident.
// ---------------------------------------------------------------------------
__global__ __launch_bounds__(512, 2) void lstm_pipe_kernel(
    const float* __restrict__ x,
    const float* __restrict__ levels,
    const float* __restrict__ wsv,
    const float* __restrict__ noise_in,
    const float* __restrict__ Wx0,
    const float* __restrict__ b0v,
    const uint4* __restrict__ pw0,
    const float* __restrict__ b1v,
    const uint4* __restrict__ pw1,
    const float* __restrict__ tanhWT,
    const float* __restrict__ tanhB,
    const float* __restrict__ linW,
    const float* __restrict__ linB,
    const float* __restrict__ noise_lab,
    __bf16* __restrict__ hs0,
    unsigned* __restrict__ flag,
    float* __restrict__ out) {
    __shared__ union {
        struct { __bf16 h0s[2][16 * 128]; float xls[WIN_SZ][16]; } a;
        struct { __bf16 h1s[2][16 * 128]; float hfl[16][129]; float featl[16][128]; } b;
    } sm;
    __shared__ unsigned flagLDS;

    const int tid  = threadIdx.x;
    const int w    = tid >> 6;
    const int lane = tid & 63;
    const int cc   = lane & 15;
    const int kl   = lane >> 4;

    int rdA[4], wrA[4];
#pragma unroll
    for (int kt = 0; kt < 4; ++kt)
        rdA[kt] = cc * 256 + ((kt * 64 + kl * 16) ^ ((cc & 7) << 4));
#pragma unroll
    for (int r = 0; r < 4; ++r) {
        const int row = kl * 4 + r;
        wrA[r] = row * 256 + (((w * 16 + cc) * 2) ^ ((row & 7) << 4));
    }

    if (blockIdx.x < NBLK) {
        // =================== layer-0 producer ===================
        const int base = blockIdx.x * BB;

        for (int i = tid; i < WIN_SZ * BB; i += 512) {
            const int t = i >> 4, m = i & 15;
            const int nn = base + m;
            float v = 0.0f;
            if (nn < N_WIN) {
                const float lev = levels[nn + WIN_SZ];
                const int tt = nn + t;
                v = logf(x[tt] / (lev * wsv[tt])) + noise_in[nn * WIN_SZ + t];
            }
            sm.a.xls[t][m] = v;
        }
        for (int i = tid; i < 2 * 16 * 128; i += 512) (&sm.a.h0s[0][0])[i] = (__bf16)0.0f;

        const bf16x8* p0 = (const bf16x8*)pw0;
        bf16x8 wB0[4][4];
#pragma unroll
        for (int ns = 0; ns < 4; ++ns)
#pragma unroll
            for (int kt = 0; kt < 4; ++kt)
                wB0[ns][kt] = p0[((w * 4 + ns) * 4 + kt) * 64 + lane];
#pragma unroll
        for (int ns = 0; ns < 4; ++ns)
#pragma unroll
            for (int kt = 0; kt < 4; ++kt)
                asm("" : "+a"(wB0[ns][kt]));

        float b0r[4], wx0r[4];
#pragma unroll
        for (int ns = 0; ns < 4; ++ns) {
            const int g = ns * 128 + w * 16 + cc;
            b0r[ns]  = b0v[g];
            wx0r[ns] = Wx0[g];
        }
        float c0r[4] = {0.f, 0.f, 0.f, 0.f};
        int goff[4];
#pragma unroll
        for (int r = 0; r < 4; ++r)
            goff[r] = (base + kl * 4 + r) * H_SZ + w * 16 + cc;
        __syncthreads();

        char* const hb0 = (char*)&sm.a.h0s[0][0];

#define L0_STEP(T, P, PUBF)                                                    \
    {                                                                          \
        const int t_ = (T);                                                    \
        const float4 xt_ = *(const float4*)&sm.a.xls[t_][kl * 4];              \
        const float xa_[4] = {xt_.x, xt_.y, xt_.z, xt_.w};                     \
        f32x4 a0_, a1_, a2_, a3_;                                              \
        _Pragma("unroll")                                                      \
        for (int r = 0; r < 4; ++r) {                                          \
            a0_[r] = b0r[0] + wx0r[0] * xa_[r];                                \
            a1_[r] = b0r[1] + wx0r[1] * xa_[r];                                \
            a2_[r] = b0r[2] + wx0r[2] * xa_[r];                                \
            a3_[r] = b0r[3] + wx0r[3] * xa_[r];                                \
        }                                                                      \
        _Pragma("unroll")                                                      \
        for (int kt = 0; kt < 4; ++kt) {                                       \
            const bf16x8 af_ = *(const bf16x8*)(hb0 + (P) * 4096 + rdA[kt]);   \
            a0_ = __builtin_amdgcn_mfma_f32_16x16x32_bf16(af_, wB0[0][kt], a0_, 0, 0, 0); \
            a1_ = __builtin_amdgcn_mfma_f32_16x16x32_bf16(af_, wB0[1][kt], a1_, 0, 0, 0); \
            a2_ = __builtin_amdgcn_mfma_f32_16x16x32_bf16(af_, wB0[2][kt], a2_, 0, 0, 0); \
            a3_ = __builtin_amdgcn_mfma_f32_16x16x32_bf16(af_, wB0[3][kt], a3_, 0, 0, 0); \
        }                                                                      \
        const int off_ = t_ * (NPAD * H_SZ);                                   \
        _Pragma("unroll")                                                      \
        for (int r = 0; r < 4; ++r) {                                          \
            const float ig_ = fsig(a0_[r]);                                    \
            const float fg_ = fsig(a1_[r]);                                    \
            const float gg_ = ftanh(a2_[r]);                                   \
            const float og_ = fsig(a3_[r]);                                    \
            const float c_  = fg_ * c0r[r] + ig_ * gg_;                        \
            c0r[r] = c_;                                                       \
            const __bf16 hb_ = (__bf16)(og_ * ftanh(c_));                      \
            *(__bf16*)(hb0 + (((P) ^ 1) * 4096) + wrA[r]) = hb_;               \
            hs0[off_ + goff[r]] = hb_;                                         \
        }                                                                      \
        if (PUBF) {                                                            \
            asm volatile("s_waitcnt vmcnt(0) lgkmcnt(0)" ::: "memory");        \
            __builtin_amdgcn_s_barrier();                                      \
            if (tid == 0) {                                                    \
                __builtin_amdgcn_fence(__ATOMIC_RELEASE, "agent");             \
                __hip_atomic_store(flag + blockIdx.x, (unsigned)(t_ + 1),      \
                                   __ATOMIC_RELAXED, __HIP_MEMORY_SCOPE_AGENT);\
            }                                                                  \
        } else {                                                               \
            LDS_BARRIER();                                                     \
        }                                                                      \
    }

        for (int tp = 0; tp < WIN_SZ / 2; ++tp) {
            L0_STEP(2 * tp, 0, false)
            L0_STEP(2 * tp + 1, 1, ((tp & 3) == 3))
        }
#undef L0_STEP
    } else {
        // =================== layer-1 consumer + head ===================
        const int bb   = blockIdx.x - NBLK;
        const int base = bb * BB;

        for (int i = tid; i < 2 * 16 * 128; i += 512) (&sm.b.h1s[0][0])[i] = (__bf16)0.0f;

        const bf16x8* p1 = (const bf16x8*)pw1;
        bf16x8 wX[4][4], wH[4][4];
#pragma unroll
        for (int ns = 0; ns < 4; ++ns)
#pragma unroll
            for (int kt = 0; kt < 4; ++kt) {
                wX[ns][kt] = p1[((w * 4 + ns) * 8 + kt) * 64 + lane];
                wH[ns][kt] = p1[((w * 4 + ns) * 8 + kt + 4) * 64 + lane];
            }
#pragma unroll
        for (int ns = 0; ns < 4; ++ns)
#pragma unroll
            for (int kt = 0; kt < 4; ++kt) {
                asm("" : "+a"(wX[ns][kt]));
                asm("" : "+a"(wH[ns][kt]));
            }

        float b1r[4];
#pragma unroll
        for (int ns = 0; ns < 4; ++ns) b1r[ns] = b1v[ns * 128 + w * 16 + cc];
        float c1r[4] = {0.f, 0.f, 0.f, 0.f};
        unsigned lastAcq = 0;

        // wait for hs0 steps {0,1} before prologue prefetch
        {
            const unsigned need_ = 2;
            if (tid == 0) {
                unsigned v;
                for (;;) {
                    v = __hip_atomic_load(flag + bb, __ATOMIC_RELAXED,
                                          __HIP_MEMORY_SCOPE_AGENT);
                    if (v >= need_) break;
                    __builtin_amdgcn_s_sleep(8);
                }
                flagLDS = v;
                __builtin_amdgcn_fence(__ATOMIC_ACQUIRE, "agent");
            }
            __syncthreads();
            lastAcq = flagLDS;
        }

        const size_t arow = (size_t)(base + cc) * H_SZ + kl * 8;
        bf16x8 fA0 = *(const bf16x8*)&hs0[arow + 0];
        bf16x8 fA1 = *(const bf16x8*)&hs0[arow + 32];
        bf16x8 fA2 = *(const bf16x8*)&hs0[arow + 64];
        bf16x8 fA3 = *(const bf16x8*)&hs0[arow + 96];
        bf16x8 fB0, fB1, fB2, fB3;
        __syncthreads();

        char* const hb1 = (char*)&sm.b.h1s[0][0];

#define L1_STEP(T, P, C0, C1, C2, C3, N0, N1, N2, N3)                          \
    {                                                                          \
        const int t_ = (T);                                                    \
        const unsigned need_ =                                                 \
            (unsigned)((t_ + 2 < WIN_SZ) ? (t_ + 2) : WIN_SZ);                 \
        if (lastAcq < need_) {                                                 \
            if (tid == 0) {                                                    \
                unsigned v_;                                                   \
                for (;;) {                                                     \
                    v_ = __hip_atomic_load(flag + bb, __ATOMIC_RELAXED,        \
                                           __HIP_MEMORY_SCOPE_AGENT);          \
                    if (v_ >= need_) break;                                    \
                    __builtin_amdgcn_s_sleep(8);                               \
                }                                                              \
                flagLDS = v_;                                                  \
                __builtin_amdgcn_fence(__ATOMIC_ACQUIRE, "agent");             \
            }                                                                  \
            __syncthreads();                                                   \
            lastAcq = flagLDS;                                                 \
        }                                                                      \
        const int tn_ = (t_ + 1 < WIN_SZ) ? (t_ + 1) : (WIN_SZ - 1);           \
        const __bf16* p_ = hs0 + (size_t)tn_ * (NPAD * H_SZ) + arow;           \
        N0 = *(const bf16x8*)(p_);                                             \
        N1 = *(const bf16x8*)(p_ + 32);                                        \
        N2 = *(const bf16x8*)(p_ + 64);                                        \
        N3 = *(const bf16x8*)(p_ + 96);                                        \
        f32x4 a0_ = {b1r[0], b1r[0], b1r[0], b1r[0]};                          \
        f32x4 a1_ = {b1r[1], b1r[1], b1r[1], b1r[1]};                          \
        f32x4 a2_ = {b1r[2], b1r[2], b1r[2], b1r[2]};                          \
        f32x4 a3_ = {b1r[3], b1r[3], b1r[3], b1r[3]};                          \
        a0_ = __builtin_amdgcn_mfma_f32_16x16x32_bf16(C0, wX[0][0], a0_, 0, 0, 0); \
        a1_ = __builtin_amdgcn_mfma_f32_16x16x32_bf16(C0, wX[1][0], a1_, 0, 0, 0); \
        a2_ = __builtin_amdgcn_mfma_f32_16x16x32_bf16(C0, wX[2][0], a2_, 0, 0, 0); \
        a3_ = __builtin_amdgcn_mfma_f32_16x16x32_bf16(C0, wX[3][0], a3_, 0, 0, 0); \
        a0_ = __builtin_amdgcn_mfma_f32_16x16x32_bf16(C1, wX[0][1], a0_, 0, 0, 0); \
        a1_ = __builtin_amdgcn_mfma_f32_16x16x32_bf16(C1, wX[1][1], a1_, 0, 0, 0); \
        a2_ = __builtin_amdgcn_mfma_f32_16x16x32_bf16(C1, wX[2][1], a2_, 0, 0, 0); \
        a3_ = __builtin_amdgcn_mfma_f32_16x16x32_bf16(C1, wX[3][1], a3_, 0, 0, 0); \
        a0_ = __builtin_amdgcn_mfma_f32_16x16x32_bf16(C2, wX[0][2], a0_, 0, 0, 0); \
        a1_ = __builtin_amdgcn_mfma_f32_16x16x32_bf16(C2, wX[1][2], a1_, 0, 0, 0); \
        a2_ = __builtin_amdgcn_mfma_f32_16x16x32_bf16(C2, wX[2][2], a2_, 0, 0, 0); \
        a3_ = __builtin_amdgcn_mfma_f32_16x16x32_bf16(C2, wX[3][2], a3_, 0, 0, 0); \
        a0_ = __builtin_amdgcn_mfma_f32_16x16x32_bf16(C3, wX[0][3], a0_, 0, 0, 0); \
        a1_ = __builtin_amdgcn_mfma_f32_16x16x32_bf16(C3, wX[1][3], a1_, 0, 0, 0); \
        a2_ = __builtin_amdgcn_mfma_f32_16x16x32_bf16(C3, wX[2][3], a2_, 0, 0, 0); \
        a3_ = __builtin_amdgcn_mfma_f32_16x16x32_bf16(C3, wX[3][3], a3_, 0, 0, 0); \
        _Pragma("unroll")                                                      \
        for (int kt = 0; kt < 4; ++kt) {                                       \
            const bf16x8 af_ = *(const bf16x8*)(hb1 + (P) * 4096 + rdA[kt]);   \
            a0_ = __builtin_amdgcn_mfma_f32_16x16x32_bf16(af_, wH[0][kt], a0_, 0, 0, 0); \
            a1_ = __builtin_amdgcn_mfma_f32_16x16x32_bf16(af_, wH[1][kt], a1_, 0, 0, 0); \
            a2_ = __builtin_amdgcn_mfma_f32_16x16x32_bf16(af_, wH[2][kt], a2_, 0, 0, 0); \
            a3_ = __builtin_amdgcn_mfma_f32_16x16x32_bf16(af_, wH[3][kt], a3_, 0, 0, 0); \
        }                                                                      \
        _Pragma("unroll")                                                      \
        for (int r = 0; r < 4; ++r) {                                          \
            const float ig_ = fsig(a0_[r]);                                    \
            const float fg_ = fsig(a1_[r]);                                    \
            const float gg_ = ftanh(a2_[r]);                                   \
            const float og_ = fsig(a3_[r]);                                    \
            const float c_  = fg_ * c1r[r] + ig_ * gg_;                        \
            c1r[r] = c_;                                                       \
            const float hv_ = og_ * ftanh(c_);                                 \
            if (t_ == WIN_SZ - 1) {                                            \
                sm.b.hfl[kl * 4 + r][w * 16 + cc] = hv_;                       \
            } else {                                                           \
                *(__bf16*)(hb1 + (((P) ^ 1) * 4096) + wrA[r]) = (__bf16)hv_;   \
            }                                                                  \
        }                                                                      \
        LDS_BARRIER();                                                         \
    }

        for (int tp = 0; tp < WIN_SZ / 2; ++tp) {
            L1_STEP(2 * tp, 0, fA0, fA1, fA2, fA3, fB0, fB1, fB2, fB3)
            L1_STEP(2 * tp + 1, 1, fB0, fB1, fB2, fB3, fA0, fA1, fA2, fA3)
        }
#undef L1_STEP

        // ---- epilogue: feat = tanh(h @ tanhW^T + tanhB) ----
        for (int p = tid; p < BB * H_SZ; p += 512) {
            const int m = p >> 7, u = p & 127;
            float acc = tanhB[u];
            for (int k = 0; k < H_SZ; ++k)
                acc += sm.b.hfl[m][k] * tanhWT[k * H_SZ + u];
            sm.b.featl[m][u] = tanhf(acc);
        }
        LDS_BARRIER();

        // ---- out = feat @ linW^T + linB; labels ----
        for (int p = tid; p < BB * OUT_SZ; p += 512) {
            const int m = p / OUT_SZ, o = p % OUT_SZ;
            const int nn = base + m;
            if (nn < N_WIN) {
                float acc = linB[o];
                for (int k = 0; k < H_SZ; ++k)
                    acc += sm.b.featl[m][k] * linW[o * H_SZ + k];
                out[nn * OUT_SZ + o] = acc;
                const float lev = levels[nn + WIN_SZ];
                const int tt = nn + WIN_SZ + o;
                out[N_WIN * OUT_SZ + nn * OUT_SZ + o] =
                    logf(x[tt] / (lev * wsv[tt])) + noise_lab[nn * OUT_SZ + o];
            }
        }
        if (bb == 0 && tid == 0)
            out[2 * N_WIN * OUT_SZ] = 0.0f;   // level_var_loss
    }
}

// ---------------------------------------------------------------------------
extern "C" void kernel_launch(void* const* d_in, const int* in_sizes, int n_in,
                              void* d_out, int out_size, void* d_ws, size_t ws_size,
                              hipStream_t stream) {
    const float* x           = (const float*)d_in[0];
    const float* lvl_raw     = (const float*)d_in[1];
    const float* seas_raw    = (const float*)d_in[2];
    const float* seas_params = (const float*)d_in[3];
    const float* noise_in    = (const float*)d_in[4];
    const float* noise_lab   = (const float*)d_in[5];
    const float* Wx0         = (const float*)d_in[6];
    const float* Wh0         = (const float*)d_in[7];
    const float* b0v         = (const float*)d_in[8];
    const float* Wx1         = (const float*)d_in[9];
    const float* Wh1         = (const float*)d_in[10];
    const float* b1v         = (const float*)d_in[11];
    const float* tanhW       = (const float*)d_in[12];
    const float* tanhB       = (const float*)d_in[13];
    const float* linW        = (const float*)d_in[14];
    const float* linB        = (const float*)d_in[15];
    float* out = (float*)d_out;

    // workspace layout (floats; pw0/pw1/hs0 16B-aligned by construction)
    float* wsf    = (float*)d_ws;
    float* levels = wsf;                                   // 1024
    float* wsv    = levels + T_LEN;                        // 1024
    float* tanhWT = wsv + T_LEN;                           // 16384
    uint4* pw0    = (uint4*)(tanhWT + H_SZ * H_SZ);        // 8192 uint4
    uint4* pw1    = pw0 + 8192;                            // 16384 uint4
    __bf16* hs0   = (__bf16*)(pw1 + 16384);                // 168*848*128 bf16
    unsigned* flags = (unsigned*)(hs0 + (size_t)WIN_SZ * NPAD * H_SZ);  // 53

    // zero the producer/consumer flags each call (ws is NOT re-poisoned
    // between replays; the protocol requires flags to start at 0)
    hipMemsetAsync(flags, 0, NBLK * sizeof(unsigned), stream);

    hipLaunchKernelGGL(pre_kernel, dim3(161), dim3(256), 0, stream,
                       x, lvl_raw, seas_raw, seas_params, Wh0, Wx1, Wh1, tanhW,
                       levels, wsv, pw0, pw1, tanhWT);
    hipLaunchKernelGGL(lstm_pipe_kernel, dim3(2 * NBLK), dim3(512), 0, stream,
                       x, levels, wsv, noise_in, Wx0, b0v, pw0,
                       b1v, pw1, tanhWT, tanhB, linW, linB, noise_lab,
                       hs0, flags, out);
}

// Round 13
// 349.449 us; speedup vs baseline: 33.3618x; 1.0237x over previous
//
#include <hip/hip_runtime.h>
#include <math.h>

#define T_LEN   1024
#define S_SEAS  168
#define H_SZ    128
#define G_SZ    512   // 4*H
#define WIN_SZ  168
#define OUT_SZ  24
#define N_WIN   833
#define BB      16
#define NBLK    ((N_WIN + BB - 1) / BB)   // 53
#define NPAD    (NBLK * BB)               // 848

typedef __attribute__((ext_vector_type(8))) __bf16 bf16x8;
typedef __attribute__((ext_vector_type(4))) float  f32x4;

__device__ __forceinline__ float fsig(float x) {
    return __fdividef(1.0f, 1.0f + __expf(-x));
}
__device__ __forceinline__ float ftanh(float x) {
    return 1.0f - __fdividef(2.0f, __expf(2.0f * x) + 1.0f);
}

// MFMA with B operand DIRECTLY from AGPR (mixed encoding, no accvgpr copies).
// D/C = VGPR f32x4, A = VGPR bf16x8, B = AGPR bf16x8.
__device__ __forceinline__ void mfma_av(f32x4& d, const bf16x8 a, const bf16x8 b) {
    asm("v_mfma_f32_16x16x32_bf16 %0, %1, %2, %0"
        : "+v"(d) : "v"(a), "a"(b));
}

// Counted-wait barrier: order LDS only; globals ride across (T3/T4).
#define LDS_BARRIER()                                        \
    do {                                                     \
        asm volatile("s_waitcnt lgkmcnt(0)" ::: "memory");   \
        __builtin_amdgcn_s_barrier();                        \
    } while (0)

// Hazard guards around the inline-asm MFMA cluster (compiler can't see
// inside asm): VALU-write -> MFMA-srcC needs ~2 waits; MFMA-write ->
// VALU-read needs ~6-10 waits.
#define MFMA_PRE_GUARD()  asm volatile("s_nop 1")
#define MFMA_POST_GUARD() asm volatile("s_nop 7\n\ts_nop 7")

// ---------------------------------------------------------------------------
// Kernel 1: parallel ES scan (block 0, r10-validated) + weight prep.
// ---------------------------------------------------------------------------
__global__ __launch_bounds__(256) void pre_kernel(
    const float* __restrict__ x,
    const float* __restrict__ lvl_raw,
    const float* __restrict__ seas_raw,
    const float* __restrict__ seas_params,
    const float* __restrict__ Wh0,
    const float* __restrict__ Wx1,
    const float* __restrict__ Wh1,
    const float* __restrict__ tanhW,
    float* __restrict__ levels,
    float* __restrict__ wsv,
    uint4* __restrict__ pw0,
    uint4* __restrict__ pw1,
    float* __restrict__ tanhWT) {
    const int t = threadIdx.x;

    if (blockIdx.x == 0) {
        __shared__ float xl[T_LEN];
        __shared__ float buf[S_SEAS];
        __shared__ float Ss[S_SEAS], Fs[S_SEAS];
        __shared__ float levCarry;
        for (int i = t; i < T_LEN; i += 256) xl[i] = x[i];
        for (int i = t; i < S_SEAS; i += 256) {
            const float w = expf(seas_params[i]);
            buf[i] = w;
            wsv[i] = w;
        }
        __syncthreads();
        const float a  = 1.0f / (1.0f + expf(-lvl_raw[0]));
        const float g  = 1.0f / (1.0f + expf(-seas_raw[0]));
        const float ca = 1.0f - a, cg = 1.0f - g;
        if (t == 0) {
            levCarry = __fdividef(xl[0], buf[0]);
            levels[0] = levCarry;
            wsv[S_SEAS] = buf[0];   // ws_full[168] = w_init[0]
        }
        __syncthreads();

        int cs = 1;
        while (cs < T_LEN) {
            const int L = min(S_SEAS, T_LEN - cs);
            float w = 0.0f;
            if (t < L) {
                const int i = cs + t;
                w = buf[i % S_SEAS];                 // final since step i-168
                Ss[t] = __fdividef(a * xl[i], w);    // t_i
                Fs[t] = ca;
            }
            __syncthreads();
            for (int d = 1; d < L; d <<= 1) {
                float sp = 0.0f, fp = 0.0f;
                const bool act = (t < L) && (t >= d);
                if (act) { sp = Ss[t - d]; fp = Fs[t - d]; }
                __syncthreads();
                if (act) {
                    Ss[t] = Ss[t] + Fs[t] * sp;
                    Fs[t] = Fs[t] * fp;
                }
                __syncthreads();
            }
            if (t < L) {
                const int i = cs + t;
                const float nl = Ss[t] + Fs[t] * levCarry;
                levels[i] = nl;
                const float nw = cg * w + __fdividef(g * xl[i], nl);
                buf[i % S_SEAS] = nw;
                if (i + S_SEAS < T_LEN) wsv[i + S_SEAS] = nw;
            }
            __syncthreads();
            if (t == 0) levCarry = Ss[L - 1] + Fs[L - 1] * levCarry;
            __syncthreads();
            cs += L;
        }
        return;
    }

    // ------- weight prep: pack MFMA B-frags (m92/m97 layout) -------
    const int idx = (blockIdx.x - 1) * 256 + t;
    auto bfr = [](float f) -> unsigned int {   // fp32 -> bf16 (RNE)
        union { float f; unsigned int u; } v; v.f = f;
        return ((v.u + 0x7FFFu + ((v.u >> 16) & 1u)) >> 16) & 0xFFFFu;
    };
    if (idx < 8192) {                       // pw0: Wh0, 128 frags
        const int l = idx & 63, f = idx >> 6;
        const int kt = f & 3, ns = (f >> 2) & 3, w = f >> 4;
        const int g = ns * 128 + w * 16 + (l & 15);
        const int kb = kt * 32 + (l >> 4) * 8;
        const float* s = Wh0 + g * H_SZ + kb;
        uint4 o;
        unsigned int* po = &o.x;
        for (int p = 0; p < 4; ++p) po[p] = bfr(s[2 * p]) | (bfr(s[2 * p + 1]) << 16);
        pw0[idx] = o;
    } else if (idx < 8192 + 16384) {        // pw1: [Wx1 (kt<4); Wh1 (kt>=4)]
        const int j = idx - 8192;
        const int l = j & 63, f = j >> 6;
        const int kt = f & 7, ns = (f >> 3) & 3, w = f >> 5;
        const int g = ns * 128 + w * 16 + (l & 15);
        const float* srcm = (kt < 4) ? Wx1 : Wh1;
        const int kb = (kt & 3) * 32 + (l >> 4) * 8;
        const float* s = srcm + g * H_SZ + kb;
        uint4 o;
        unsigned int* po = &o.x;
        for (int p = 0; p < 4; ++p) po[p] = bfr(s[2 * p]) | (bfr(s[2 * p + 1]) << 16);
        pw1[j] = o;
    } else if (idx < 8192 + 16384 + 16384) {  // tanh_W transpose (fp32)
        const int j = idx - 8192 - 16384;
        const int m = j >> 7, k = j & 127;
        tanhWT[k * H_SZ + m] = tanhW[j];
    }
}

// ---------------------------------------------------------------------------
// Kernel 2: producer/consumer 2-layer LSTM pipeline in ONE launch (r12
// structure). Inner-loop MFMAs now use the inline-asm mixed AGPR-B form
// (mfma_av) to eliminate accvgpr copies. Publish cadence 8->4 steps.
// ---------------------------------------------------------------------------
__global__ __launch_bounds__(512, 2) void lstm_pipe_kernel(
    const float* __restrict__ x,
    const float* __restrict__ levels,
    const float* __restrict__ wsv,
    const float* __restrict__ noise_in,
    const float* __restrict__ Wx0,
    const float* __restrict__ b0v,
    const uint4* __restrict__ pw0,
    const float* __restrict__ b1v,
    const uint4* __restrict__ pw1,
    const float* __restrict__ tanhWT,
    const float* __restrict__ tanhB,
    const float* __restrict__ linW,
    const float* __restrict__ linB,
    const float* __restrict__ noise_lab,
    __bf16* __restrict__ hs0,
    unsigned* __restrict__ flag,
    float* __restrict__ out) {
    __shared__ union {
        struct { __bf16 h0s[2][16 * 128]; float xls[WIN_SZ][16]; } a;
        struct { __bf16 h1s[2][16 * 128]; float hfl[16][129]; float featl[16][128]; } b;
    } sm;
    __shared__ unsigned flagLDS;

    const int tid  = threadIdx.x;
    const int w    = tid >> 6;
    const int lane = tid & 63;
    const int cc   = lane & 15;
    const int kl   = lane >> 4;

    int rdA[4], wrA[4];
#pragma unroll
    for (int kt = 0; kt < 4; ++kt)
        rdA[kt] = cc * 256 + ((kt * 64 + kl * 16) ^ ((cc & 7) << 4));
#pragma unroll
    for (int r = 0; r < 4; ++r) {
        const int row = kl * 4 + r;
        wrA[r] = row * 256 + (((w * 16 + cc) * 2) ^ ((row & 7) << 4));
    }

    if (blockIdx.x < NBLK) {
        // =================== layer-0 producer ===================
        const int base = blockIdx.x * BB;

        for (int i = tid; i < WIN_SZ * BB; i += 512) {
            const int t = i >> 4, m = i & 15;
            const int nn = base + m;
            float v = 0.0f;
            if (nn < N_WIN) {
                const float lev = levels[nn + WIN_SZ];
                const int tt = nn + t;
                v = logf(x[tt] / (lev * wsv[tt])) + noise_in[nn * WIN_SZ + t];
            }
            sm.a.xls[t][m] = v;
        }
        for (int i = tid; i < 2 * 16 * 128; i += 512) (&sm.a.h0s[0][0])[i] = (__bf16)0.0f;

        const bf16x8* p0 = (const bf16x8*)pw0;
        bf16x8 wB0[4][4];
#pragma unroll
        for (int ns = 0; ns < 4; ++ns)
#pragma unroll
            for (int kt = 0; kt < 4; ++kt)
                wB0[ns][kt] = p0[((w * 4 + ns) * 4 + kt) * 64 + lane];
#pragma unroll
        for (int ns = 0; ns < 4; ++ns)
#pragma unroll
            for (int kt = 0; kt < 4; ++kt)
                asm("" : "+a"(wB0[ns][kt]));

        float b0r[4], wx0r[4];
#pragma unroll
        for (int ns = 0; ns < 4; ++ns) {
            const int g = ns * 128 + w * 16 + cc;
            b0r[ns]  = b0v[g];
            wx0r[ns] = Wx0[g];
        }
        float c0r[4] = {0.f, 0.f, 0.f, 0.f};
        int goff[4];
#pragma unroll
        for (int r = 0; r < 4; ++r)
            goff[r] = (base + kl * 4 + r) * H_SZ + w * 16 + cc;
        __syncthreads();

        char* const hb0 = (char*)&sm.a.h0s[0][0];

#define L0_STEP(T, P, PUBF)                                                    \
    {                                                                          \
        const int t_ = (T);                                                    \
        const float4 xt_ = *(const float4*)&sm.a.xls[t_][kl * 4];              \
        const float xa_[4] = {xt_.x, xt_.y, xt_.z, xt_.w};                     \
        f32x4 a0_, a1_, a2_, a3_;                                              \
        _Pragma("unroll")                                                      \
        for (int r = 0; r < 4; ++r) {                                          \
            a0_[r] = b0r[0] + wx0r[0] * xa_[r];                                \
            a1_[r] = b0r[1] + wx0r[1] * xa_[r];                                \
            a2_[r] = b0r[2] + wx0r[2] * xa_[r];                                \
            a3_[r] = b0r[3] + wx0r[3] * xa_[r];                                \
        }                                                                      \
        MFMA_PRE_GUARD();                                                      \
        _Pragma("unroll")                                                      \
        for (int kt = 0; kt < 4; ++kt) {                                       \
            const bf16x8 af_ = *(const bf16x8*)(hb0 + (P) * 4096 + rdA[kt]);   \
            mfma_av(a0_, af_, wB0[0][kt]);                                     \
            mfma_av(a1_, af_, wB0[1][kt]);                                     \
            mfma_av(a2_, af_, wB0[2][kt]);                                     \
            mfma_av(a3_, af_, wB0[3][kt]);                                     \
        }                                                                      \
        MFMA_POST_GUARD();                                                     \
        const int off_ = t_ * (NPAD * H_SZ);                                   \
        _Pragma("unroll")                                                      \
        for (int r = 0; r < 4; ++r) {                                          \
            const float ig_ = fsig(a0_[r]);                                    \
            const float fg_ = fsig(a1_[r]);                                    \
            const float gg_ = ftanh(a2_[r]);                                   \
            const float og_ = fsig(a3_[r]);                                    \
            const float c_  = fg_ * c0r[r] + ig_ * gg_;                        \
            c0r[r] = c_;                                                       \
            const __bf16 hb_ = (__bf16)(og_ * ftanh(c_));                      \
            *(__bf16*)(hb0 + (((P) ^ 1) * 4096) + wrA[r]) = hb_;               \
            hs0[off_ + goff[r]] = hb_;                                         \
        }                                                                      \
        if (PUBF) {                                                            \
            asm volatile("s_waitcnt vmcnt(0) lgkmcnt(0)" ::: "memory");        \
            __builtin_amdgcn_s_barrier();                                      \
            if (tid == 0) {                                                    \
                __builtin_amdgcn_fence(__ATOMIC_RELEASE, "agent");             \
                __hip_atomic_store(flag + blockIdx.x, (unsigned)(t_ + 1),      \
                                   __ATOMIC_RELAXED, __HIP_MEMORY_SCOPE_AGENT);\
            }                                                                  \
        } else {                                                               \
            LDS_BARRIER();                                                     \
        }                                                                      \
    }

        for (int tp = 0; tp < WIN_SZ / 2; ++tp) {
            L0_STEP(2 * tp, 0, false)
            L0_STEP(2 * tp + 1, 1, ((tp & 1) == 1))   // publish every 4 steps
        }
#undef L0_STEP
    } else {
        // =================== layer-1 consumer + head ===================
        const int bb   = blockIdx.x - NBLK;
        const int base = bb * BB;

        for (int i = tid; i < 2 * 16 * 128; i += 512) (&sm.b.h1s[0][0])[i] = (__bf16)0.0f;

        const bf16x8* p1 = (const bf16x8*)pw1;
        bf16x8 wX[4][4], wH[4][4];
#pragma unroll
        for (int ns = 0; ns < 4; ++ns)
#pragma unroll
            for (int kt = 0; kt < 4; ++kt) {
                wX[ns][kt] = p1[((w * 4 + ns) * 8 + kt) * 64 + lane];
                wH[ns][kt] = p1[((w * 4 + ns) * 8 + kt + 4) * 64 + lane];
            }
#pragma unroll
        for (int ns = 0; ns < 4; ++ns)
#pragma unroll
            for (int kt = 0; kt < 4; ++kt) {
                asm("" : "+a"(wX[ns][kt]));
                asm("" : "+a"(wH[ns][kt]));
            }

        float b1r[4];
#pragma unroll
        for (int ns = 0; ns < 4; ++ns) b1r[ns] = b1v[ns * 128 + w * 16 + cc];
        float c1r[4] = {0.f, 0.f, 0.f, 0.f};
        unsigned lastAcq = 0;

        // wait for hs0 steps {0,1} before prologue prefetch
        {
            const unsigned need_ = 2;
            if (tid == 0) {
                unsigned v;
                for (;;) {
                    v = __hip_atomic_load(flag + bb, __ATOMIC_RELAXED,
                                          __HIP_MEMORY_SCOPE_AGENT);
                    if (v >= need_) break;
                    __builtin_amdgcn_s_sleep(8);
                }
                flagLDS = v;
                __builtin_amdgcn_fence(__ATOMIC_ACQUIRE, "agent");
            }
            __syncthreads();
            lastAcq = flagLDS;
        }

        const size_t arow = (size_t)(base + cc) * H_SZ + kl * 8;
        bf16x8 fA0 = *(const bf16x8*)&hs0[arow + 0];
        bf16x8 fA1 = *(const bf16x8*)&hs0[arow + 32];
        bf16x8 fA2 = *(const bf16x8*)&hs0[arow + 64];
        bf16x8 fA3 = *(const bf16x8*)&hs0[arow + 96];
        bf16x8 fB0, fB1, fB2, fB3;
        __syncthreads();

        char* const hb1 = (char*)&sm.b.h1s[0][0];

#define L1_STEP(T, P, C0, C1, C2, C3, N0, N1, N2, N3)                          \
    {                                                                          \
        const int t_ = (T);                                                    \
        const unsigned need_ =                                                 \
            (unsigned)((t_ + 2 < WIN_SZ) ? (t_ + 2) : WIN_SZ);                 \
        if (lastAcq < need_) {                                                 \
            if (tid == 0) {                                                    \
                unsigned v_;                                                   \
                for (;;) {                                                     \
                    v_ = __hip_atomic_load(flag + bb, __ATOMIC_RELAXED,        \
                                           __HIP_MEMORY_SCOPE_AGENT);          \
                    if (v_ >= need_) break;                                    \
                    __builtin_amdgcn_s_sleep(8);                               \
                }                                                              \
                flagLDS = v_;                                                  \
                __builtin_amdgcn_fence(__ATOMIC_ACQUIRE, "agent");             \
            }                                                                  \
            __syncthreads();                                                   \
            lastAcq = flagLDS;                                                 \
        }                                                                      \
        const int tn_ = (t_ + 1 < WIN_SZ) ? (t_ + 1) : (WIN_SZ - 1);           \
        const __bf16* p_ = hs0 + (size_t)tn_ * (NPAD * H_SZ) + arow;           \
        N0 = *(const bf16x8*)(p_);                                             \
        N1 = *(const bf16x8*)(p_ + 32);                                        \
        N2 = *(const bf16x8*)(p_ + 64);                                        \
        N3 = *(const bf16x8*)(p_ + 96);                                        \
        f32x4 a0_ = {b1r[0], b1r[0], b1r[0], b1r[0]};                          \
        f32x4 a1_ = {b1r[1], b1r[1], b1r[1], b1r[1]};                          \
        f32x4 a2_ = {b1r[2], b1r[2], b1r[2], b1r[2]};                          \
        f32x4 a3_ = {b1r[3], b1r[3], b1r[3], b1r[3]};                          \
        MFMA_PRE_GUARD();                                                      \
        mfma_av(a0_, C0, wX[0][0]);                                            \
        mfma_av(a1_, C0, wX[1][0]);                                            \
        mfma_av(a2_, C0, wX[2][0]);                                            \
        mfma_av(a3_, C0, wX[3][0]);                                            \
        mfma_av(a0_, C1, wX[0][1]);                                            \
        mfma_av(a1_, C1, wX[1][1]);                                            \
        mfma_av(a2_, C1, wX[2][1]);                                            \
        mfma_av(a3_, C1, wX[3][1]);                                            \
        mfma_av(a0_, C2, wX[0][2]);                                            \
        mfma_av(a1_, C2, wX[1][2]);                                            \
        mfma_av(a2_, C2, wX[2][2]);                                            \
        mfma_av(a3_, C2, wX[3][2]);                                            \
        mfma_av(a0_, C3, wX[0][3]);                                            \
        mfma_av(a1_, C3, wX[1][3]);                                            \
        mfma_av(a2_, C3, wX[2][3]);                                            \
        mfma_av(a3_, C3, wX[3][3]);                                            \
        _Pragma("unroll")                                                      \
        for (int kt = 0; kt < 4; ++kt) {                                       \
            const bf16x8 af_ = *(const bf16x8*)(hb1 + (P) * 4096 + rdA[kt]);   \
            mfma_av(a0_, af_, wH[0][kt]);                                      \
            mfma_av(a1_, af_, wH[1][kt]);                                      \
            mfma_av(a2_, af_, wH[2][kt]);                                      \
            mfma_av(a3_, af_, wH[3][kt]);                                      \
        }                                                                      \
        MFMA_POST_GUARD();                                                     \
        _Pragma("unroll")                                                      \
        for (int r = 0; r < 4; ++r) {                                          \
            const float ig_ = fsig(a0_[r]);                                    \
            const float fg_ = fsig(a1_[r]);                                    \
            const float gg_ = ftanh(a2_[r]);                                   \
            const float og_ = fsig(a3_[r]);                                    \
            const float c_  = fg_ * c1r[r] + ig_ * gg_;                        \
            c1r[r] = c_;                                                       \
            const float hv_ = og_ * ftanh(c_);                                 \
            if (t_ == WIN_SZ - 1) {                                            \
                sm.b.hfl[kl * 4 + r][w * 16 + cc] = hv_;                       \
            } else {                                                           \
                *(__bf16*)(hb1 + (((P) ^ 1) * 4096) + wrA[r]) = (__bf16)hv_;   \
            }                                                                  \
        }                                                                      \
        LDS_BARRIER();                                                         \
    }

        for (int tp = 0; tp < WIN_SZ / 2; ++tp) {
            L1_STEP(2 * tp, 0, fA0, fA1, fA2, fA3, fB0, fB1, fB2, fB3)
            L1_STEP(2 * tp + 1, 1, fB0, fB1, fB2, fB3, fA0, fA1, fA2, fA3)
        }
#undef L1_STEP

        // ---- epilogue: feat = tanh(h @ tanhW^T + tanhB) ----
        for (int p = tid; p < BB * H_SZ; p += 512) {
            const int m = p >> 7, u = p & 127;
            float acc = tanhB[u];
            for (int k = 0; k < H_SZ; ++k)
                acc += sm.b.hfl[m][k] * tanhWT[k * H_SZ + u];
            sm.b.featl[m][u] = tanhf(acc);
        }
        LDS_BARRIER();

        // ---- out = feat @ linW^T + linB; labels ----
        for (int p = tid; p < BB * OUT_SZ; p += 512) {
            const int m = p / OUT_SZ, o = p % OUT_SZ;
            const int nn = base + m;
            if (nn < N_WIN) {
                float acc = linB[o];
                for (int k = 0; k < H_SZ; ++k)
                    acc += sm.b.featl[m][k] * linW[o * H_SZ + k];
                out[nn * OUT_SZ + o] = acc;
                const float lev = levels[nn + WIN_SZ];
                const int tt = nn + WIN_SZ + o;
                out[N_WIN * OUT_SZ + nn * OUT_SZ + o] =
                    logf(x[tt] / (lev * wsv[tt])) + noise_lab[nn * OUT_SZ + o];
            }
        }
        if (bb == 0 && tid == 0)
            out[2 * N_WIN * OUT_SZ] = 0.0f;   // level_var_loss
    }
}

// ---------------------------------------------------------------------------
extern "C" void kernel_launch(void* const* d_in, const int* in_sizes, int n_in,
                              void* d_out, int out_size, void* d_ws, size_t ws_size,
                              hipStream_t stream) {
    const float* x           = (const float*)d_in[0];
    const float* lvl_raw     = (const float*)d_in[1];
    const float* seas_raw    = (const float*)d_in[2];
    const float* seas_params = (const float*)d_in[3];
    const float* noise_in    = (const float*)d_in[4];
    const float* noise_lab   = (const float*)d_in[5];
    const float* Wx0         = (const float*)d_in[6];
    const float* Wh0         = (const float*)d_in[7];
    const float* b0v         = (const float*)d_in[8];
    const float* Wx1         = (const float*)d_in[9];
    const float* Wh1         = (const float*)d_in[10];
    const float* b1v         = (const float*)d_in[11];
    const float* tanhW       = (const float*)d_in[12];
    const float* tanhB       = (const float*)d_in[13];
    const float* linW        = (const float*)d_in[14];
    const float* linB        = (const float*)d_in[15];
    float* out = (float*)d_out;

    // workspace layout (floats; pw0/pw1/hs0 16B-aligned by construction)
    float* wsf    = (float*)d_ws;
    float* levels = wsf;                                   // 1024
    float* wsv    = levels + T_LEN;                        // 1024
    float* tanhWT = wsv + T_LEN;                           // 16384
    uint4* pw0    = (uint4*)(tanhWT + H_SZ * H_SZ);        // 8192 uint4
    uint4* pw1    = pw0 + 8192;                            // 16384 uint4
    __bf16* hs0   = (__bf16*)(pw1 + 16384);                // 168*848*128 bf16
    unsigned* flags = (unsigned*)(hs0 + (size_t)WIN_SZ * NPAD * H_SZ);  // 53

    // zero the producer/consumer flags each call (ws is NOT re-poisoned
    // between replays; the protocol requires flags to start at 0)
    hipMemsetAsync(flags, 0, NBLK * sizeof(unsigned), stream);

    hipLaunchKernelGGL(pre_kernel, dim3(161), dim3(256), 0, stream,
                       x, lvl_raw, seas_raw, seas_params, Wh0, Wx1, Wh1, tanhW,
                       levels, wsv, pw0, pw1, tanhWT);
    hipLaunchKernelGGL(lstm_pipe_kernel, dim3(2 * NBLK), dim3(512), 0, stream,
                       x, levels, wsv, noise_in, Wx0, b0v, pw0,
                       b1v, pw1, tanhWT, tanhB, linW, linB, noise_lab,
                       hs0, flags, out);
}